// Round 1
// baseline (88.659 us; speedup 1.0000x reference)
//
#include <hip/hip_runtime.h>
#include <hip/hip_bf16.h>

#define BB 4
#define NN 2048
#define FIN 512
#define FOUT 128
#define NEGV -9e15f
#define ALPHAV 0.2f

typedef __attribute__((ext_vector_type(8))) short bf16x8;
typedef __attribute__((ext_vector_type(4))) float f32x4;

__device__ __forceinline__ unsigned short f32_to_bf16(float f) {
    unsigned int u = __float_as_uint(f);
    unsigned int r = (u + 0x7FFFu + ((u >> 16) & 1u)) >> 16;   // RNE
    return (unsigned short)r;
}

// ---------------- Kernel A: h = input @ W  (f32, tiled) ----------------
// block: 16 rows x 128 cols, 256 threads; grid = (B*N)/16 = 512
__global__ void __launch_bounds__(256) k_h(const float* __restrict__ x,
                                           const float* __restrict__ W,
                                           float* __restrict__ h) {
    __shared__ float xs[16 * FIN];      // 32 KB
    int row0 = blockIdx.x * 16;
    const float4* src = (const float4*)(x + (size_t)row0 * FIN);
    float4* dst = (float4*)xs;
#pragma unroll
    for (int i = 0; i < 8; i++) dst[threadIdx.x + i * 256] = src[threadIdx.x + i * 256];
    __syncthreads();

    int o = threadIdx.x & 127;
    int g = threadIdx.x >> 7;           // 0/1 -> rows g*8 .. g*8+7
    float acc[8] = {0.f,0.f,0.f,0.f,0.f,0.f,0.f,0.f};
    const float* wp = W + o;
    for (int k = 0; k < FIN; k += 4) {
        float w0 = wp[(k + 0) * FOUT];
        float w1 = wp[(k + 1) * FOUT];
        float w2 = wp[(k + 2) * FOUT];
        float w3 = wp[(k + 3) * FOUT];
#pragma unroll
        for (int r = 0; r < 8; r++) {
            float4 xv = *(const float4*)&xs[(g * 8 + r) * FIN + k];
            acc[r] = fmaf(xv.x, w0, acc[r]);
            acc[r] = fmaf(xv.y, w1, acc[r]);
            acc[r] = fmaf(xv.z, w2, acc[r]);
            acc[r] = fmaf(xv.w, w3, acc[r]);
        }
    }
#pragma unroll
    for (int r = 0; r < 8; r++)
        h[(size_t)(row0 + g * 8 + r) * FOUT + o] = acc[r];
}

// ---------------- Kernel T: t1 = h@a1, t2 = h@a2 ----------------
// block 256 = 4 waves; each wave 16 rows (lane&15), 4 lanes/row over col-quarters
__global__ void __launch_bounds__(256) k_t(const float* __restrict__ h,
                                           const float* __restrict__ a1,
                                           const float* __restrict__ a2,
                                           float* __restrict__ t1,
                                           float* __restrict__ t2) {
    int wv = threadIdx.x >> 6, l = threadIdx.x & 63;
    int row = blockIdx.x * 64 + wv * 16 + (l & 15);
    int c0 = (l >> 4) * 32;
    const float* hp = h + (size_t)row * FOUT + c0;
    float s1 = 0.f, s2 = 0.f;
#pragma unroll
    for (int c = 0; c < 32; c += 4) {
        float4 hv = *(const float4*)(hp + c);
        float4 u = *(const float4*)(a1 + c0 + c);
        float4 v = *(const float4*)(a2 + c0 + c);
        s1 += hv.x * u.x + hv.y * u.y + hv.z * u.z + hv.w * u.w;
        s2 += hv.x * v.x + hv.y * v.y + hv.z * v.z + hv.w * v.w;
    }
    s1 += __shfl_xor(s1, 16); s1 += __shfl_xor(s1, 32);
    s2 += __shfl_xor(s2, 16); s2 += __shfl_xor(s2, 32);
    if ((l >> 4) == 0) { t1[row] = s1; t2[row] = s2; }
}

// ---------------- Kernel R: repack h -> bf16 B-fragment layout ----------------
// frag layout for mfma_f32_16x16x32_bf16 B-operand: lane l, elem jj holds
//   B[k = (l>>4)*8+jj][n = l&15]   => hb[((b*64+jt)*8 + t_o)*512 + l*8 + jj]
//   = h[b][jt*32 + (l>>4)*8+jj][t_o*16 + (l&15)]
__global__ void k_repack(const float* __restrict__ h, unsigned short* __restrict__ hb) {
    __shared__ float hs[32 * FOUT];     // 16 KB
    int b = blockIdx.x >> 6;
    int jt = blockIdx.x & 63;
    const float4* src = (const float4*)(h + ((size_t)b * NN + jt * 32) * FOUT);
    float4* dst = (float4*)hs;
    for (int i = threadIdx.x; i < 1024; i += 64) dst[i] = src[i];
    __syncthreads();
    int l = threadIdx.x;
    int lr = l & 15, lg = l >> 4;
#pragma unroll
    for (int t_o = 0; t_o < 8; t_o++) {
        unsigned short v[8];
#pragma unroll
        for (int jj = 0; jj < 8; jj++) {
            float f = hs[(lg * 8 + jj) * FOUT + t_o * 16 + lr];
            v[jj] = f32_to_bf16(f);
        }
        *(uint4*)(hb + ((size_t)(blockIdx.x * 8 + t_o) * 64 + l) * 8) = *(const uint4*)v;
    }
}

// ---------------- Kernel B: fused masked-softmax attention + PV (MFMA) ----------------
// grid = B * (N/16) = 512 blocks; block = 256 (4 waves)
// wave wv handles the same 16 i-rows, o-tiles {2wv, 2wv+1} (32 cols)
__global__ void __launch_bounds__(256) k_attn(const int* __restrict__ adj,
                                              const float* __restrict__ t1g,
                                              const float* __restrict__ t2g,
                                              const unsigned short* __restrict__ hb,
                                              const int* __restrict__ d1p,
                                              const int* __restrict__ d2p,
                                              float* __restrict__ out) {
    int blk = blockIdx.x;
    int b = blk >> 7;
    int i0 = (blk & 127) * 16;
    int wv = threadIdx.x >> 6;
    int l = threadIdx.x & 63;
    int lr = l & 15, lg = l >> 4;
    int d1 = d1p[0], d2 = d2p[0];
    int irow = i0 + lr;
    float t1v = t1g[b * NN + irow];
    const int* adjRow = adj + (size_t)(b * NN + irow) * NN + lg * 8;
    const float* t2p = t2g + b * NN + lg * 8;
    // frag base for this b, t_o = 2*wv: stride per jt = 8*512 ushorts
    const unsigned short* hb0 = hb + (size_t)b * (NN / 32) * 8 * 512 + (size_t)(2 * wv) * 512 + l * 8;

    float m = NEGV, s = 0.f;
    f32x4 acc0 = {0.f, 0.f, 0.f, 0.f};
    f32x4 acc1 = {0.f, 0.f, 0.f, 0.f};

#pragma unroll 2
    for (int jt = 0; jt < NN / 32; jt++) {
        int4 av0 = *(const int4*)(adjRow + jt * 32);
        int4 av1 = *(const int4*)(adjRow + jt * 32 + 4);
        float4 tb0 = *(const float4*)(t2p + jt * 32);
        float4 tb1 = *(const float4*)(t2p + jt * 32 + 4);
        bf16x8 hf0 = *(const bf16x8*)(hb0 + (size_t)jt * 4096);
        bf16x8 hf1 = *(const bf16x8*)(hb0 + (size_t)jt * 4096 + 512);

        int ai[8] = {av0.x, av0.y, av0.z, av0.w, av1.x, av1.y, av1.z, av1.w};
        float tv[8] = {tb0.x, tb0.y, tb0.z, tb0.w, tb1.x, tb1.y, tb1.z, tb1.w};
        float att[8];
#pragma unroll
        for (int jj = 0; jj < 8; jj++) {
            float v = t1v + tv[jj];
            float e = v >= 0.f ? v : ALPHAV * v;
            att[jj] = (ai[jj] == d1 || ai[jj] == d2) ? e : NEGV;
        }
        float mx = att[0];
#pragma unroll
        for (int jj = 1; jj < 8; jj++) mx = fmaxf(mx, att[jj]);
        mx = fmaxf(mx, __shfl_xor(mx, 16));
        mx = fmaxf(mx, __shfl_xor(mx, 32));
        float mnew = fmaxf(m, mx);
        float scale = __expf(m - mnew);     // m==mnew -> 1; first-tile NEGV-NEGV=0 -> 1
        m = mnew;
        float psum = 0.f;
        bf16x8 pa;
#pragma unroll
        for (int jj = 0; jj < 8; jj++) {
            float p = __expf(att[jj] - m);  // masked & m==NEGV -> exp(0)=1 (matches ref)
            psum += p;
            pa[jj] = (short)f32_to_bf16(p);
        }
        s = s * scale + psum;
        // rescale accumulators: C row r = lg*4+reg needs scale from lane r
        float sc[4];
#pragma unroll
        for (int r = 0; r < 4; r++) sc[r] = __shfl(scale, lg * 4 + r);
#pragma unroll
        for (int r = 0; r < 4; r++) { acc0[r] *= sc[r]; acc1[r] *= sc[r]; }
        acc0 = __builtin_amdgcn_mfma_f32_16x16x32_bf16(pa, hf0, acc0, 0, 0, 0);
        acc1 = __builtin_amdgcn_mfma_f32_16x16x32_bf16(pa, hf1, acc1, 0, 0, 0);
    }

    float stot = s;
    stot += __shfl_xor(stot, 16);
    stot += __shfl_xor(stot, 32);
#pragma unroll
    for (int r = 0; r < 4; r++) {
        float sr = __shfl(stot, lg * 4 + r);
        float inv = 1.f / sr;
        int row = i0 + lg * 4 + r;
        out[(size_t)(b * NN + row) * FOUT + (2 * wv) * 16 + lr] = acc0[r] * inv;
        out[(size_t)(b * NN + row) * FOUT + (2 * wv + 1) * 16 + lr] = acc1[r] * inv;
    }
}

extern "C" void kernel_launch(void* const* d_in, const int* in_sizes, int n_in,
                              void* d_out, int out_size, void* d_ws, size_t ws_size,
                              hipStream_t stream) {
    const float* x  = (const float*)d_in[0];
    const float* W  = (const float*)d_in[1];
    const float* a1 = (const float*)d_in[2];
    const float* a2 = (const float*)d_in[3];
    const int* adj  = (const int*)d_in[4];
    // d_in[5] = adj_tree (unused by reference forward)
    const int* d1p  = (const int*)d_in[6];
    const int* d2p  = (const int*)d_in[7];
    float* out = (float*)d_out;

    char* ws = (char*)d_ws;
    float* h             = (float*)(ws);                              // 4 MB
    unsigned short* hbuf = (unsigned short*)(ws + 4u * 1024 * 1024);  // 2 MB
    float* t1            = (float*)(ws + 6u * 1024 * 1024);           // 32 KB
    float* t2            = (float*)(ws + 6u * 1024 * 1024 + 32 * 1024);

    k_h<<<dim3(512), dim3(256), 0, stream>>>(x, W, h);
    k_t<<<dim3(128), dim3(256), 0, stream>>>(h, a1, a2, t1, t2);
    k_repack<<<dim3(256), dim3(64), 0, stream>>>(h, hbuf);
    k_attn<<<dim3(512), dim3(256), 0, stream>>>(adj, t1, t2, hbuf, d1p, d2p, out);
}

// Round 2
// 58.734 us; speedup vs baseline: 1.5095x; 1.5095x over previous
//
#include <hip/hip_runtime.h>
#include <hip/hip_bf16.h>

#define BB 4
#define NN 2048
#define FIN 512
#define FOUT 128
#define NEGV -9e15f
#define ALPHAV 0.2f

typedef __attribute__((ext_vector_type(8))) short bf16x8;
typedef __attribute__((ext_vector_type(4))) float f32x4;

__device__ __forceinline__ unsigned cvt_pk_bf16(float lo, float hi) {
    unsigned r;
    asm("v_cvt_pk_bf16_f32 %0, %1, %2" : "=v"(r) : "v"(lo), "v"(hi));
    return r;   // low16 = bf16(lo), high16 = bf16(hi), RNE
}

// ---------------- Kernel 1: h = x@W (f32), then t1/t2 dots + bf16 frag repack ----------------
// grid = B*N/32 = 256 blocks, 512 threads (8 waves). Block computes 32 rows x 128 cols.
__global__ void __launch_bounds__(512) k_hT(const float* __restrict__ x,
                                            const float* __restrict__ W,
                                            const float* __restrict__ a1,
                                            const float* __restrict__ a2,
                                            unsigned short* __restrict__ hb,
                                            float* __restrict__ t1,
                                            float* __restrict__ t2) {
    __shared__ float xs[32 * FIN];        // 64 KB
    __shared__ float hs[32 * 129];        // 16.5 KB, padded stride
    int blk = blockIdx.x;                 // == b*64 + jt
    int tid = threadIdx.x;
    size_t row0 = (size_t)blk * 32;

    // stage x tile
    {
        const float4* src = (const float4*)(x + row0 * FIN);
        float4* dst = (float4*)xs;
#pragma unroll
        for (int i = 0; i < 8; i++) dst[tid + i * 512] = src[tid + i * 512];
    }
    __syncthreads();

    int wv = tid >> 6;            // 0..7 -> rows wv*4 .. wv*4+3
    int o2 = tid & 63;
    int ocol = o2 * 2;

    float acc[4][2];
#pragma unroll
    for (int r = 0; r < 4; r++) { acc[r][0] = 0.f; acc[r][1] = 0.f; }

    for (int k = 0; k < FIN; k += 4) {
        float2 wk0 = *(const float2*)&W[(k + 0) * FOUT + ocol];
        float2 wk1 = *(const float2*)&W[(k + 1) * FOUT + ocol];
        float2 wk2 = *(const float2*)&W[(k + 2) * FOUT + ocol];
        float2 wk3 = *(const float2*)&W[(k + 3) * FOUT + ocol];
#pragma unroll
        for (int r = 0; r < 4; r++) {
            float4 xv = *(const float4*)&xs[(wv * 4 + r) * FIN + k];   // broadcast read
            acc[r][0] = fmaf(xv.x, wk0.x, acc[r][0]);
            acc[r][0] = fmaf(xv.y, wk1.x, acc[r][0]);
            acc[r][0] = fmaf(xv.z, wk2.x, acc[r][0]);
            acc[r][0] = fmaf(xv.w, wk3.x, acc[r][0]);
            acc[r][1] = fmaf(xv.x, wk0.y, acc[r][1]);
            acc[r][1] = fmaf(xv.y, wk1.y, acc[r][1]);
            acc[r][1] = fmaf(xv.z, wk2.y, acc[r][1]);
            acc[r][1] = fmaf(xv.w, wk3.y, acc[r][1]);
        }
    }

    // t1/t2: per-row dot with a1,a2 — butterfly over the 64-lane o dimension
    {
        float2 a1v = *(const float2*)&a1[ocol];
        float2 a2v = *(const float2*)&a2[ocol];
        float p1[4], p2[4];
#pragma unroll
        for (int r = 0; r < 4; r++) {
            p1[r] = acc[r][0] * a1v.x + acc[r][1] * a1v.y;
            p2[r] = acc[r][0] * a2v.x + acc[r][1] * a2v.y;
        }
#pragma unroll
        for (int off = 1; off < 64; off <<= 1) {
#pragma unroll
            for (int r = 0; r < 4; r++) {
                p1[r] += __shfl_xor(p1[r], off);
                p2[r] += __shfl_xor(p2[r], off);
            }
        }
        if (o2 == 0) {
#pragma unroll
            for (int r = 0; r < 4; r++) {
                t1[row0 + wv * 4 + r] = p1[r];
                t2[row0 + wv * 4 + r] = p2[r];
            }
        }
    }

    // bounce h through LDS (2-way-free padded stride 129)
#pragma unroll
    for (int r = 0; r < 4; r++) {
        hs[(wv * 4 + r) * 129 + ocol]     = acc[r][0];
        hs[(wv * 4 + r) * 129 + ocol + 1] = acc[r][1];
    }
    __syncthreads();

    // repack to MFMA B-fragment layout: wave wv handles o-tile t_o = wv.
    // hb[(blk*8 + t_o)*512 + l*8 + jj] = bf16( h[jrow=(l>>4)*8+jj][t_o*16 + (l&15)] )
    {
        int l = tid & 63;
        int lr = l & 15, lg = l >> 4;
        float f[8];
#pragma unroll
        for (int jj = 0; jj < 8; jj++)
            f[jj] = hs[(lg * 8 + jj) * 129 + wv * 16 + lr];
        unsigned u[4];
#pragma unroll
        for (int w = 0; w < 4; w++) u[w] = cvt_pk_bf16(f[2 * w], f[2 * w + 1]);
        *(uint4*)(hb + ((size_t)(blk * 8 + wv) * 64 + l) * 8) = *(const uint4*)u;
    }
}

// ---------------- Kernel 2: fused masked-softmax attention + PV (MFMA) ----------------
// grid = B*N/16 = 512 blocks, 256 threads (4 waves).
// All waves share the same 16 i-rows; wave wv processes j-tiles jt ≡ wv (mod 4),
// each wave owns all 8 o-tiles. Cross-wave flash combine in LDS at the end.
__global__ void __launch_bounds__(256) k_attn(const int* __restrict__ adj,
                                              const float* __restrict__ t1g,
                                              const float* __restrict__ t2g,
                                              const unsigned short* __restrict__ hb,
                                              const int* __restrict__ d1p,
                                              const int* __restrict__ d2p,
                                              float* __restrict__ out) {
    __shared__ float accbuf[4][16][132];    // 33792 B, 2-way-free padding
    __shared__ float lds_m[4][16];
    __shared__ float lds_s[4][16];
    __shared__ float lds_inv[16];

    int blk = blockIdx.x;
    int b = blk >> 7;
    int i0 = (blk & 127) * 16;
    int tid = threadIdx.x;
    int wv = tid >> 6;
    int l = tid & 63;
    int lr = l & 15, lg = l >> 4;
    int d1 = d1p[0], d2 = d2p[0];

    float t1v = t1g[b * NN + i0 + lr];
    const int* adjRow = adj + ((size_t)(b * NN + i0 + lr)) * NN + lg * 8;
    const float* t2p = t2g + b * NN + lg * 8;
    const unsigned short* hbbase = hb + (size_t)b * 64 * 4096 + (size_t)l * 8;

    float m = NEGV, s = 0.f;
    f32x4 acc[8];
#pragma unroll
    for (int t = 0; t < 8; t++) acc[t] = (f32x4){0.f, 0.f, 0.f, 0.f};

#pragma unroll 2
    for (int jt = wv; jt < NN / 32; jt += 4) {
        int4 av0 = *(const int4*)(adjRow + jt * 32);
        int4 av1 = *(const int4*)(adjRow + jt * 32 + 4);
        float4 tb0 = *(const float4*)(t2p + jt * 32);
        float4 tb1 = *(const float4*)(t2p + jt * 32 + 4);
        bf16x8 hf[8];
#pragma unroll
        for (int t = 0; t < 8; t++)
            hf[t] = *(const bf16x8*)(hbbase + (size_t)jt * 4096 + t * 512);

        int ai[8] = {av0.x, av0.y, av0.z, av0.w, av1.x, av1.y, av1.z, av1.w};
        float tv[8] = {tb0.x, tb0.y, tb0.z, tb0.w, tb1.x, tb1.y, tb1.z, tb1.w};
        float att[8];
#pragma unroll
        for (int jj = 0; jj < 8; jj++) {
            float v = t1v + tv[jj];
            float e = fmaxf(v, ALPHAV * v);          // leaky relu (alpha<1)
            att[jj] = (ai[jj] == d1 || ai[jj] == d2) ? e : NEGV;
        }
        float mx = att[0];
#pragma unroll
        for (int jj = 1; jj < 8; jj++) mx = fmaxf(mx, att[jj]);
        mx = fmaxf(mx, __shfl_xor(mx, 16));
        mx = fmaxf(mx, __shfl_xor(mx, 32));

        if (__any(mx > m + 8.f)) {                   // T13 defer-max
            float mnew = fmaxf(m, mx);
            float scale = __expf(m - mnew);
            m = mnew;
            s *= scale;
            float scr[4];
#pragma unroll
            for (int r = 0; r < 4; r++) scr[r] = __shfl(scale, lg * 4 + r);
#pragma unroll
            for (int t = 0; t < 8; t++)
#pragma unroll
                for (int r = 0; r < 4; r++) acc[t][r] *= scr[r];
        }

        float p[8];
        float psum = 0.f;
#pragma unroll
        for (int jj = 0; jj < 8; jj++) {
            p[jj] = __expf(att[jj] - m);             // masked & m==NEGV -> exp(0)=1 (matches ref)
            psum += p[jj];
        }
        s += psum;

        unsigned u[4];
#pragma unroll
        for (int w = 0; w < 4; w++) u[w] = cvt_pk_bf16(p[2 * w], p[2 * w + 1]);
        bf16x8 pa = *(const bf16x8*)u;
#pragma unroll
        for (int t = 0; t < 8; t++)
            acc[t] = __builtin_amdgcn_mfma_f32_16x16x32_bf16(pa, hf[t], acc[t], 0, 0, 0);
    }

    // cross-wave flash combine
    s += __shfl_xor(s, 16);
    s += __shfl_xor(s, 32);
    if (l < 16) { lds_m[wv][lr] = m; lds_s[wv][lr] = s; }
    __syncthreads();

    float mt = fmaxf(fmaxf(lds_m[0][lr], lds_m[1][lr]),
                     fmaxf(lds_m[2][lr], lds_m[3][lr]));
    if (wv == 0 && l < 16) {
        float st = 0.f;
#pragma unroll
        for (int w = 0; w < 4; w++) st += lds_s[w][lr] * __expf(lds_m[w][lr] - mt);
        lds_inv[lr] = 1.0f / st;
    }
    float scale = __expf(m - mt);
    float scr[4];
#pragma unroll
    for (int r = 0; r < 4; r++) scr[r] = __shfl(scale, lg * 4 + r);
#pragma unroll
    for (int t = 0; t < 8; t++)
#pragma unroll
        for (int r = 0; r < 4; r++)
            accbuf[wv][lg * 4 + r][t * 16 + lr] = acc[t][r] * scr[r];
    __syncthreads();

#pragma unroll
    for (int e = 0; e < 8; e++) {
        int flat = tid + e * 256;
        int row = flat >> 7;
        int col = flat & 127;
        float sum = accbuf[0][row][col] + accbuf[1][row][col]
                  + accbuf[2][row][col] + accbuf[3][row][col];
        out[((size_t)b * NN + i0 + row) * FOUT + col] = sum * lds_inv[row];
    }
}

extern "C" void kernel_launch(void* const* d_in, const int* in_sizes, int n_in,
                              void* d_out, int out_size, void* d_ws, size_t ws_size,
                              hipStream_t stream) {
    const float* x  = (const float*)d_in[0];
    const float* W  = (const float*)d_in[1];
    const float* a1 = (const float*)d_in[2];
    const float* a2 = (const float*)d_in[3];
    const int* adj  = (const int*)d_in[4];
    // d_in[5] = adj_tree (unused by reference forward)
    const int* d1p  = (const int*)d_in[6];
    const int* d2p  = (const int*)d_in[7];
    float* out = (float*)d_out;

    char* ws = (char*)d_ws;
    unsigned short* hbuf = (unsigned short*)(ws);                     // 2 MB
    float* t1            = (float*)(ws + 2u * 1024 * 1024);           // 32 KB
    float* t2            = (float*)(ws + 2u * 1024 * 1024 + 32 * 1024);

    k_hT<<<dim3(256), dim3(512), 0, stream>>>(x, W, a1, a2, hbuf, t1, t2);
    k_attn<<<dim3(512), dim3(256), 0, stream>>>(adj, t1, t2, hbuf, d1p, d2p, out);
}